// Round 8
// baseline (650.157 us; speedup 1.0000x reference)
//
#include <hip/hip_runtime.h>

typedef unsigned char  u8;
typedef unsigned short u16;
typedef unsigned int   u32;

#define NN   16384     // nodes
#define EE   262144    // edges
#define RR   9         // relations
#define DIN  384
#define DH   768
#define KSU  3456      // RR*DIN
#define KS   3520      // KSU + 9 cnt cols + pad to 64 (BK=64 GEMM)

typedef float  f32x4 __attribute__((ext_vector_type(4)));
typedef float  f32x2 __attribute__((ext_vector_type(2)));
typedef __bf16 b16x8 __attribute__((ext_vector_type(8)));

__device__ __forceinline__ u16 f2bf(float f){
  u32 u = __builtin_bit_cast(u32, f);
  u += 0x7fffu + ((u >> 16) & 1u);          // RNE
  return (u16)(u >> 16);
}
__device__ __forceinline__ float bflo(u32 u){ return __builtin_bit_cast(float, u << 16); }
__device__ __forceinline__ float bfhi(u32 u){ return __builtin_bit_cast(float, u & 0xffff0000u); }
__device__ __forceinline__ u32 pk2(float a, float b){
  return (u32)f2bf(a) | ((u32)f2bf(b) << 16);
}
// async global->LDS, 16B per lane; LDS dest = wave-uniform base + lane*16
__device__ __forceinline__ void gll16(const void* g, void* l){
  __builtin_amdgcn_global_load_lds((const __attribute__((address_space(1))) void*)g,
                                   (__attribute__((address_space(3))) void*)l, 16, 0, 0);
}

// ---------------- CSR scan ----------------
__global__ __launch_bounds__(1024) void k_scan(const int* __restrict__ counts,
                                               int* __restrict__ starts,
                                               int* __restrict__ cursor){
  __shared__ int tot[1024];
  const int t = threadIdx.x;
  int loc[16]; int s = 0;
  #pragma unroll
  for (int j=0;j<16;j++){ loc[j] = counts[t*16+j]; s += loc[j]; }
  tot[t] = s;
  __syncthreads();
  for (int o=1;o<1024;o<<=1){
    int v = (t>=o) ? tot[t-o] : 0;
    __syncthreads();
    tot[t] += v;
    __syncthreads();
  }
  int run = tot[t] - s;  // exclusive prefix
  #pragma unroll
  for (int j=0;j<16;j++){ starts[t*16+j] = run; cursor[t*16+j] = run; run += loc[j]; }
  if (t == 1023) starts[NN] = run;
}

// scatter edges into CSR order; emit pre-gathered src/rtype arrays
__global__ void k_place(const int* __restrict__ src, const int* __restrict__ dst,
                        const int* __restrict__ et, int* __restrict__ cursor,
                        int* __restrict__ srcp, int* __restrict__ rp){
  const int e = blockIdx.x*256 + threadIdx.x;
  if (e < EE){
    const int p = atomicAdd(&cursor[dst[e]], 1);
    srcp[p] = src[e];
    rp[p]   = et[e];
  }
}

// ------------- one region-split kernel: edge count + all bf16 conversions ---
// region 0: counts[dst[e]]++                          (EE)
// region 1: xb  = bf16(x) packed pairs                (NN*DIN/2 u32)
// region 2: Wst[hh][k] stacked rel_W/rel_b (bf16)     (DH*KS elems)
// region 3: WB  = [mp_lin_W; mp_self_W] (bf16)        (2*DH*DH elems)
#define NXP (NN*DIN/2)       // 3145728
#define NW1 (DH*KS)          // 2703360
#define NW2 (2*DH*DH)        // 1179648
__global__ __launch_bounds__(256) void k_conv(const int* __restrict__ edst,
                                              const float* __restrict__ x,
                                              const float* __restrict__ rW,
                                              const float* __restrict__ rb,
                                              const float* __restrict__ lW,
                                              const float* __restrict__ sW,
                                              int* __restrict__ counts,
                                              u32* __restrict__ xb,
                                              u16* __restrict__ Wst,
                                              u16* __restrict__ WB){
  long j = (long)blockIdx.x*256 + threadIdx.x;
  if (j < EE){ atomicAdd(&counts[edst[j]], 1); return; }
  j -= EE;
  if (j < NXP){
    const f32x2 v = ((const f32x2*)x)[j];
    xb[j] = pk2(v.x, v.y);
    return;
  }
  j -= NXP;
  if (j < NW1){
    const int hh = (int)(j / KS);
    const int k  = (int)(j - (long)hh*KS);
    float v;
    if (k < KSU){ const int r = k / DIN; const int d = k - r*DIN;
                  v = rW[((long)r*DH + hh)*DIN + d]; }
    else if (k < KSU + RR){ const int r = k - KSU; v = rb[(long)r*DH + hh]; }
    else v = 0.f;
    Wst[(long)hh*KS + k] = f2bf(v);
    return;
  }
  j -= NW1;
  const float v = (j < DH*DH) ? lW[j] : sW[j - DH*DH];
  WB[j] = f2bf(v);
}

// ---- phase1 fused (dot + axpy): one wave per dst node, bf16, VGPR acc ----
// norm_p = dot(x[i], x[srcp[p]]) / nc[rp[p]]
// s[i, r*384+d] = sum_p norm_p * x[srcp[p], d]; s[i,3456+r] = sum norm_p
// 2-edge interleaved shuffle chains for ILP; explicit A/B slots (constant
// register indices only — runtime-indexed arrays get demoted to scratch, R4).
// No min-waves clamp: R4/R5 showed forced VGPR caps spill the 54-reg acc.
__global__ __launch_bounds__(256) void k_phase1f(const u32* __restrict__ xb,
                                                 const int* __restrict__ srcp,
                                                 const int* __restrict__ rp,
                                                 const float* __restrict__ nc,
                                                 const int* __restrict__ starts,
                                                 u16* __restrict__ s){
  const int w = threadIdx.x >> 6, l = threadIdx.x & 63;
  const int i = blockIdx.x*4 + w;
  const u32* xr = xb + (long)i*192;             // own row (dst), 384 bf16
  float xdf[6];
  {
    const u32 a = xr[l], b = xr[64+l], c = xr[128+l];
    xdf[0]=bflo(a); xdf[1]=bfhi(a); xdf[2]=bflo(b);
    xdf[3]=bfhi(b); xdf[4]=bflo(c); xdf[5]=bfhi(c);
  }
  float ncv[RR];
  #pragma unroll
  for (int r=0;r<RR;r++) ncv[r] = 1.0f / nc[r];
  float acc[RR][6];
  float cacc[RR];
  #pragma unroll
  for (int r=0;r<RR;r++){
    cacc[r] = 0.f;
    #pragma unroll
    for (int j=0;j<6;j++) acc[r][j] = 0.f;
  }
  const int e0 = starts[i], np = starts[i+1] - e0;

  u32 A0=0,A1=0,A2=0,B0=0,B1=0,B2=0; int Ar=0, Br=0;
  if (np > 0){
    const u32* xs = xb + (long)srcp[e0]*192;
    A0=xs[l]; A1=xs[64+l]; A2=xs[128+l]; Ar=rp[e0];
  }
  if (np > 1){
    const u32* xs = xb + (long)srcp[e0+1]*192;
    B0=xs[l]; B1=xs[64+l]; B2=xs[128+l]; Br=rp[e0+1];
  }

  #define AXPY(R,CF,P) { const float nm_=(P)*ncv[R]; cacc[R]+=nm_; \
    acc[R][0]+=nm_*CF[0]; acc[R][1]+=nm_*CF[1]; acc[R][2]+=nm_*CF[2]; \
    acc[R][3]+=nm_*CF[3]; acc[R][4]+=nm_*CF[4]; acc[R][5]+=nm_*CF[5]; }
  #define SW(CF,P,RV) switch (RV){ \
      case 0: AXPY(0,CF,P) break; case 1: AXPY(1,CF,P) break; \
      case 2: AXPY(2,CF,P) break; case 3: AXPY(3,CF,P) break; \
      case 4: AXPY(4,CF,P) break; case 5: AXPY(5,CF,P) break; \
      case 6: AXPY(6,CF,P) break; case 7: AXPY(7,CF,P) break; \
      default: AXPY(8,CF,P) break; }

  for (int p=0; p<np; p+=2){
    const bool h2 = (p+1 < np);
    const u32 a0=A0, a1=A1, a2=A2; const int ra=Ar;
    const u32 b0=B0, b1=B1, b2=B2; const int rb=Br;
    if (p+2 < np){                      // refill A (edge p+2) — loads in flight
      const u32* xs = xb + (long)srcp[e0+p+2]*192;
      A0=xs[l]; A1=xs[64+l]; A2=xs[128+l]; Ar=rp[e0+p+2];
    }
    if (p+3 < np){                      // refill B (edge p+3)
      const u32* xs = xb + (long)srcp[e0+p+3]*192;
      B0=xs[l]; B1=xs[64+l]; B2=xs[128+l]; Br=rp[e0+p+3];
    }
    float fa[6], fb[6];
    fa[0]=bflo(a0); fa[1]=bfhi(a0); fa[2]=bflo(a1);
    fa[3]=bfhi(a1); fa[4]=bflo(a2); fa[5]=bfhi(a2);
    fb[0]=bflo(b0); fb[1]=bfhi(b0); fb[2]=bflo(b1);
    fb[3]=bfhi(b1); fb[4]=bflo(b2); fb[5]=bfhi(b2);
    float pa = xdf[0]*fa[0] + xdf[1]*fa[1] + xdf[2]*fa[2]
             + xdf[3]*fa[3] + xdf[4]*fa[4] + xdf[5]*fa[5];
    float pb = xdf[0]*fb[0] + xdf[1]*fb[1] + xdf[2]*fb[2]
             + xdf[3]*fb[3] + xdf[4]*fb[4] + xdf[5]*fb[5];
    #pragma unroll
    for (int o=32;o;o>>=1){             // two interleaved butterfly chains
      pa += __shfl_xor(pa, o);
      pb += __shfl_xor(pb, o);
    }
    SW(fa,pa,ra)
    if (h2){ SW(fb,pb,rb) }
  }
  #undef SW
  #undef AXPY

  u16* srow = s + (long)i*KS;
  #pragma unroll
  for (int r=0;r<RR;r++){
    #pragma unroll
    for (int seg=0;seg<3;seg++)
      ((u32*)(srow + r*DIN + seg*128))[l] = pk2(acc[r][seg*2], acc[r][seg*2+1]);
  }
  // tail cols 3456..3519: 9 cnt cols then zeros; lane l<32 writes pair (2l,2l+1)
  float cv0 = 0.f, cv1 = 0.f;
  #pragma unroll
  for (int r=0;r<RR;r++){
    cv0 = (2*l   == r) ? cacc[r] : cv0;
    cv1 = (2*l+1 == r) ? cacc[r] : cv1;
  }
  if (l < 32) ((u32*)(srow + KSU))[l] = pk2(cv0, cv1);
}

// ---------------- bf16 GEMM, BK=64: C = A * B^T (both K-major) --------------
// 128x128 tile, 4 waves (2x2), 64x64/wave via 4x4 of mfma 16x16x32, 2 K-substeps.
// 55 barriers (K=3520) vs 109 at BK=32 — amortizes the vmcnt(0) barrier drain.
// XOR chunk swizzle (chunk ^ row&7) applied on the GLOBAL source address
// (gll16 dest is forced lane-contiguous); bijective per row; ds_read 2-way.
// grid: x = M-tile (fast) -> same-A blocks share an XCD (id%8).
// MODE 0: O0 = relu(C) bf16, stride DH           (gemm1: x1)
// MODE 1: n<768 -> O0 = C+b0[n]; else O1 = C+b1  (gemm2: hm / selfx)
template<int MODE>
__global__ __launch_bounds__(256, 2)
void k_gemm_bt(const u16* __restrict__ A, const u16* __restrict__ B,
               int M, int N, int K,
               u16* __restrict__ O0, u16* __restrict__ O1,
               const float* __restrict__ b0, const float* __restrict__ b1)
{
  __shared__ __align__(16) u16 As[128*64];   // 16 KB
  __shared__ __align__(16) u16 Bs[128*64];   // 16 KB
  const int t  = threadIdx.x;
  const int wv = t >> 6;
  const int ln = t & 63;
  const int wm = wv >> 1, wn = wv & 1;
  const long m0 = (long)blockIdx.x * 128;
  const long n0 = (long)blockIdx.y * 128;

  const int srl = ln >> 3;                   // staging row within 8-row group
  const int scc = ((ln & 7) ^ srl) * 8;      // swizzled source col chunk (elems)

  f32x4 acc[4][4];
  #pragma unroll
  for (int i=0;i<4;i++)
    #pragma unroll
    for (int j=0;j<4;j++) acc[i][j] = {0.f,0.f,0.f,0.f};

  const int fr = ln & 15, fq = ln >> 4;
  const int nk = K >> 6;
  for (int kb=0; kb<nk; ++kb){
    const long k0 = (long)kb * 64;
    #pragma unroll
    for (int q=0;q<4;q++){
      const int rbase = wv*32 + q*8;
      const int row   = rbase + srl;
      gll16(A + (m0 + row)*(long)K + k0 + scc, &As[rbase*64]);
      gll16(B + (n0 + row)*(long)K + k0 + scc, &Bs[rbase*64]);
    }
    __syncthreads();
    b16x8 av0[4], bv0[4], av1[4], bv1[4];
    #pragma unroll
    for (int i=0;i<4;i++){
      const int pc0 = ((0*4 + fq) ^ (fr & 7))*8;
      const int pc1 = ((1*4 + fq) ^ (fr & 7))*8;
      av0[i] = *(const b16x8*)&As[(wm*64 + i*16 + fr)*64 + pc0];
      bv0[i] = *(const b16x8*)&Bs[(wn*64 + i*16 + fr)*64 + pc0];
      av1[i] = *(const b16x8*)&As[(wm*64 + i*16 + fr)*64 + pc1];
      bv1[i] = *(const b16x8*)&Bs[(wn*64 + i*16 + fr)*64 + pc1];
    }
    #pragma unroll
    for (int i=0;i<4;i++)
      #pragma unroll
      for (int j=0;j<4;j++)
        acc[i][j] = __builtin_amdgcn_mfma_f32_16x16x32_bf16(av0[i], bv0[j], acc[i][j], 0, 0, 0);
    #pragma unroll
    for (int i=0;i<4;i++)
      #pragma unroll
      for (int j=0;j<4;j++)
        acc[i][j] = __builtin_amdgcn_mfma_f32_16x16x32_bf16(av1[i], bv1[j], acc[i][j], 0, 0, 0);
    __syncthreads();
  }

  #pragma unroll
  for (int i=0;i<4;i++){
    #pragma unroll
    for (int j=0;j<4;j++){
      #pragma unroll
      for (int r=0;r<4;r++){
        const long m = m0 + wm*64 + i*16 + fq*4 + r;   // C row = quad*4+reg
        const long n = n0 + wn*64 + j*16 + fr;         // C col = lane&15
        float v = acc[i][j][r];
        if (MODE == 0){
          v = v > 0.f ? v : 0.f;
          O0[m*DH + n] = f2bf(v);
        } else {
          if (n < DH) O0[m*DH + n]      = f2bf(v + b0[n]);
          else        O1[m*DH + (n-DH)] = f2bf(v + b1[n-DH]);
        }
      }
    }
  }
}

// ---------------- phase2 + mean-pool fused ----------------
// per node i: v = relu( sum_{p in seg(i)} hm[srcp[p]] + sfx[i] ); pooled += v
// 8 nodes/block (2 per wave, accumulated in regs), LDS block-reduce, then
// global atomics spread over 8 pooled copies (blockIdx&7) to cut contention.
__global__ __launch_bounds__(256, 4) void k_phase2(const u32* __restrict__ hm32,
                                                   const u32* __restrict__ sfx32,
                                                   const int* __restrict__ srcp,
                                                   const int* __restrict__ starts,
                                                   float* __restrict__ pooled8){
  const int w = threadIdx.x >> 6, l = threadIdx.x & 63;
  const int t = threadIdx.x;
  __shared__ float pl[DH];
  #pragma unroll
  for (int k=0;k<3;k++) pl[t + 256*k] = 0.f;
  __syncthreads();

  float po[12];
  #pragma unroll
  for (int j=0;j<12;j++) po[j] = 0.f;

  for (int q=0;q<2;q++){
    const int i = blockIdx.x*8 + w*2 + q;
    float a[12];
    #pragma unroll
    for (int j=0;j<12;j++) a[j] = 0.f;
    const int e0 = starts[i], np = starts[i+1] - e0;

    u32 A0=0,A1=0,A2=0,A3=0,A4=0,A5=0;
    u32 B0=0,B1=0,B2=0,B3=0,B4=0,B5=0;
    if (np > 0){
      const u32* hr = hm32 + (long)srcp[e0]*384;
      A0=hr[l]; A1=hr[64+l]; A2=hr[128+l]; A3=hr[192+l]; A4=hr[256+l]; A5=hr[320+l];
    }
    if (np > 1){
      const u32* hr = hm32 + (long)srcp[e0+1]*384;
      B0=hr[l]; B1=hr[64+l]; B2=hr[128+l]; B3=hr[192+l]; B4=hr[256+l]; B5=hr[320+l];
    }
    for (int p=0; p<np; p+=2){
      a[0]+=bflo(A0); a[1]+=bfhi(A0); a[2]+=bflo(A1); a[3] +=bfhi(A1);
      a[4]+=bflo(A2); a[5]+=bfhi(A2); a[6] +=bflo(A3); a[7] +=bfhi(A3);
      a[8]+=bflo(A4); a[9]+=bfhi(A4); a[10]+=bflo(A5); a[11]+=bfhi(A5);
      if (p+2 < np){
        const u32* hr = hm32 + (long)srcp[e0+p+2]*384;
        A0=hr[l]; A1=hr[64+l]; A2=hr[128+l]; A3=hr[192+l]; A4=hr[256+l]; A5=hr[320+l];
      }
      if (p+1 < np){
        a[0]+=bflo(B0); a[1]+=bfhi(B0); a[2] +=bflo(B1); a[3] +=bfhi(B1);
        a[4]+=bflo(B2); a[5]+=bfhi(B2); a[6] +=bflo(B3); a[7] +=bfhi(B3);
        a[8]+=bflo(B4); a[9]+=bfhi(B4); a[10]+=bflo(B5); a[11]+=bfhi(B5);
        if (p+3 < np){
          const u32* hr = hm32 + (long)srcp[e0+p+3]*384;
          B0=hr[l]; B1=hr[64+l]; B2=hr[128+l]; B3=hr[192+l]; B4=hr[256+l]; B5=hr[320+l];
        }
      }
    }
    const u32* sr = sfx32 + (long)i*384;
    #pragma unroll
    for (int j=0;j<6;j++){
      const u32 sv = sr[l + 64*j];
      float v0 = a[2*j]   + bflo(sv);
      float v1 = a[2*j+1] + bfhi(sv);
      po[2*j]   += v0 > 0.f ? v0 : 0.f;
      po[2*j+1] += v1 > 0.f ? v1 : 0.f;
    }
  }
  #pragma unroll
  for (int j=0;j<6;j++){
    atomicAdd(&pl[2*l   + 128*j], po[2*j]);
    atomicAdd(&pl[2*l+1 + 128*j], po[2*j+1]);
  }
  __syncthreads();
  float* pd = pooled8 + (blockIdx.x & 7)*DH;
  #pragma unroll
  for (int k=0;k<3;k++) atomicAdd(&pd[t + 256*k], pl[t + 256*k]);
}

__global__ __launch_bounds__(256) void k_final(const float* __restrict__ pooled8,
                                               const float* __restrict__ oW,
                                               const float* __restrict__ ob,
                                               float* __restrict__ out){
  __shared__ float ps[DH];
  __shared__ float red[256];
  const int t = threadIdx.x;
  for (int h=t; h<DH; h+=256){
    float s = 0.f;
    #pragma unroll
    for (int c=0;c<8;c++) s += pooled8[c*DH + h];
    ps[h] = s;
  }
  __syncthreads();
  for (int c=0;c<5;c++){
    float p = 0.f;
    for (int h=t; h<DH; h+=256) p += ps[h]*oW[c*DH + h];
    red[t] = p; __syncthreads();
    for (int o=128;o;o>>=1){ if (t<o) red[t]+=red[t+o]; __syncthreads(); }
    if (t == 0) out[c] = red[0]*(1.f/(float)NN) + ob[c];
    __syncthreads();
  }
}

// ---------------- launch ----------------
extern "C" void kernel_launch(void* const* d_in, const int* in_sizes, int n_in,
                              void* d_out, int out_size, void* d_ws, size_t ws_size,
                              hipStream_t stream)
{
  (void)in_sizes; (void)n_in; (void)out_size; (void)ws_size;
  const float* x     = (const float*)d_in[0];
  const int*   ei    = (const int*)  d_in[1];   // [2][E]: row0=src, row1=dst
  const int*   et    = (const int*)  d_in[2];
  const float* relW  = (const float*)d_in[3];
  const float* relb  = (const float*)d_in[4];
  const float* nc    = (const float*)d_in[5];
  const float* linW  = (const float*)d_in[6];
  const float* linb  = (const float*)d_in[7];
  const float* selfW = (const float*)d_in[8];
  const float* selfb = (const float*)d_in[9];
  const float* outW  = (const float*)d_in[10];
  const float* outb  = (const float*)d_in[11];
  float* out = (float*)d_out;

  // workspace layout; counts+pooled8 adjacent -> one memset; xb aliases x1
  // (dead until gemm1 writes it); hm/sfx alias S (dead after gemm1)
  u8* w = (u8*)d_ws;
  int*   counts  = (int*)(w + 0);              // 64 KB
  float* pooled8 = (float*)(w + 65536);        // 24576 B
  int*   starts  = (int*)(w + 90112);          // 65540 B
  int*   cursor  = (int*)(w + 155904);         // 64 KB
  int*   srcp    = (int*)(w + 221440);         // 1 MB
  int*   rp      = (int*)(w + 1270016);        // 1 MB
  u16*   Wst     = (u16*)(w + 2318592);        // 768*3520*2  = 5406720
  u16*   WB      = (u16*)(w + 7725312);        // 1536*768*2  = 2359296
  u16*   x1      = (u16*)(w + 10084608);       // 16384*768*2 = 25165824
  u32*   xb      = (u32*)x1;                   // alias: 12.6 MB, dead before gemm1
  u16*   S       = (u16*)(w + 35250432);       // 16384*3520*2 = 115343360
  u16*   hm      = S;                          // alias: 25.2 MB
  u16*   sfx     = (u16*)(w + 35250432 + 25165824);

  const int* esrc = ei;
  const int* edst = ei + EE;

  hipMemsetAsync(w, 0, 90112, stream);         // counts + pooled8 in one shot

  k_conv  <<<(EE + NXP + NW1 + NW2)/256, 256, 0, stream>>>(
      edst, x, relW, relb, linW, selfW, counts, xb, Wst, WB);
  k_scan  <<<1, 1024, 0, stream>>>(counts, starts, cursor);
  k_place <<<EE/256, 256, 0, stream>>>(esrc, edst, et, cursor, srcp, rp);
  k_phase1f<<<NN/4, 256, 0, stream>>>(xb, srcp, rp, nc, starts, S);
  k_gemm_bt<0><<<dim3(NN/128, DH/128), 256, 0, stream>>>(
      S, Wst, NN, DH, KS, x1, (u16*)nullptr, (const float*)nullptr, (const float*)nullptr);
  k_gemm_bt<1><<<dim3(NN/128, 2*DH/128), 256, 0, stream>>>(
      x1, WB, NN, 2*DH, DH, hm, sfx, linb, selfb);
  k_phase2<<<NN/8, 256, 0, stream>>>((const u32*)hm, (const u32*)sfx, srcp, starts, pooled8);
  k_final <<<1, 256, 0, stream>>>(pooled8, outW, outb, out);
}